// Round 6
// baseline (434.896 us; speedup 1.0000x reference)
//
#include <hip/hip_runtime.h>
#include <math.h>

#define D_MODEL 768
#define D_STATE 16
#define D_CONV  4
#define D_INNER 1536
#define BATCH   2
#define SEQ     512
#define M_ROWS  (BATCH * SEQ)            // 1024
#define N_XZ    (2 * D_INNER)            // 3072
#define N_XDBL  (D_INNER + 2 * D_STATE)  // 1568

typedef short  short8 __attribute__((ext_vector_type(8)));
typedef float  f32x4  __attribute__((ext_vector_type(4)));
typedef unsigned short ushort_t;
typedef ushort_t ushort4_t __attribute__((ext_vector_type(4)));

// ---- manual bf16 helpers (RNE), raw ushort storage ----
__device__ __forceinline__ ushort_t f2bf(float f) {
    unsigned int u = __float_as_uint(f);
    return (ushort_t)((u + 0x7fffu + ((u >> 16) & 1u)) >> 16);
}
__device__ __forceinline__ float bf2f(ushort_t s) {
    return __uint_as_float((unsigned int)s << 16);
}
__device__ __forceinline__ void split1(float x, ushort_t& h, ushort_t& l) {
    h = f2bf(x);
    l = f2bf(x - bf2f(h));
}
__device__ __forceinline__ void atomAddF(float* p, float v) {
    unsafeAtomicAdd(p, v);   // HW global_atomic fp32 add (CDNA)
}

// ---------------------------------------------------------------------------
// Split fp32 -> (hi, lo) bf16.  n multiple of 1024; 4 elements/thread.
// ---------------------------------------------------------------------------
__global__ __launch_bounds__(256) void split_kernel(
    const float* __restrict__ in, ushort_t* __restrict__ hi,
    ushort_t* __restrict__ lo, int n)
{
    int i = (blockIdx.x * 256 + threadIdx.x) * 4;
    if (i >= n) return;
    float4 v = *(const float4*)(in + i);
    ushort_t h0,h1,h2,h3,l0,l1,l2,l3;
    split1(v.x,h0,l0); split1(v.y,h1,l1); split1(v.z,h2,l2); split1(v.w,h3,l3);
    hi[i+0]=h0; hi[i+1]=h1; hi[i+2]=h2; hi[i+3]=h3;
    lo[i+0]=l0; lo[i+1]=l1; lo[i+2]=l2; lo[i+3]=l3;
}

// ---------------------------------------------------------------------------
// Split-bf16 MFMA GEMM — one wave per block, 64x64 tile, no LDS, no barriers,
// SINGLE-buffered fragments (spill-free; latency hidden by wave count).
// grid.z = K-chunk index; each chunk covers kc columns of K.
// MODE 0: direct fp32 store (single chunk).  MODE 1: atomicAdd into accum.
// A (M,K), B (N,K) hi/lo bf16.  3-product split: Al*Bh + Ah*Bl + Ah*Bh.
// N tail: B row clamped for loads, store guarded.
// ---------------------------------------------------------------------------
template <int MODE>
__global__ __launch_bounds__(64, 2) void gemm_mfma(
    const ushort_t* __restrict__ Ah, const ushort_t* __restrict__ Al, int lda,
    const ushort_t* __restrict__ Bh, const ushort_t* __restrict__ Bl, int ldb,
    float* __restrict__ C, int ldc,
    int N, int kc)
{
    const int lane = threadIdx.x;
    const int bm = blockIdx.y * 64;
    const int bn = blockIdx.x * 64;
    const int lr = lane & 15;
    const int lq = lane >> 4;
    const long k0 = (long)blockIdx.z * kc + lq * 8;

    long oA[4], oB[4];
#pragma unroll
    for (int i = 0; i < 4; ++i) {
        oA[i] = (long)(bm + i * 16 + lr) * lda + k0;
        int rB = bn + i * 16 + lr;
        if (rB >= N) rB = N - 1;               // clamp: in-buffer, discarded
        oB[i] = (long)rB * ldb + k0;
    }

    f32x4 acc[4][4] = {};
    for (int kk = 0; kk < kc; kk += 32) {
        short8 ah[4], al[4], bh[4], bl[4];
#pragma unroll
        for (int i = 0; i < 4; ++i) {
            ah[i] = *(const short8*)(Ah + oA[i] + kk);
            al[i] = *(const short8*)(Al + oA[i] + kk);
            bh[i] = *(const short8*)(Bh + oB[i] + kk);
            bl[i] = *(const short8*)(Bl + oB[i] + kk);
        }
#pragma unroll
        for (int mt = 0; mt < 4; ++mt)
#pragma unroll
            for (int nt = 0; nt < 4; ++nt) {
                acc[mt][nt] = __builtin_amdgcn_mfma_f32_16x16x32_bf16(al[mt], bh[nt], acc[mt][nt], 0, 0, 0);
                acc[mt][nt] = __builtin_amdgcn_mfma_f32_16x16x32_bf16(ah[mt], bl[nt], acc[mt][nt], 0, 0, 0);
                acc[mt][nt] = __builtin_amdgcn_mfma_f32_16x16x32_bf16(ah[mt], bh[nt], acc[mt][nt], 0, 0, 0);
            }
    }

    // C/D layout: col = lane&15, row = (lane>>4)*4 + reg  [m89/m91]
    const int col0 = lane & 15;
    const int quad = lane >> 4;
#pragma unroll
    for (int mt = 0; mt < 4; ++mt)
#pragma unroll
        for (int nt = 0; nt < 4; ++nt)
#pragma unroll
            for (int r = 0; r < 4; ++r) {
                int row = bm + mt * 16 + quad * 4 + r;
                int col = bn + nt * 16 + col0;
                if (col >= N) continue;
                if (MODE == 0) C[(long)row * ldc + col] = acc[mt][nt][r];
                else           atomAddF(&C[(long)row * ldc + col], acc[mt][nt][r]);
            }
}

// ---------------------------------------------------------------------------
// Epilogue for GEMM4: deltaT[d][m] = softplus(acc[d][m] + b_dt[d]).
// acc/deltaT are (1536, 1024) fp32.
// ---------------------------------------------------------------------------
__global__ __launch_bounds__(256) void ep_softplus_kernel(
    const float* __restrict__ acc, const float* __restrict__ b_dt,
    float* __restrict__ deltaT)
{
    int i = (blockIdx.x * 256 + threadIdx.x) * 4;
    if (i >= D_INNER * M_ROWS) return;
    int row = i >> 10;                      // /1024, same for all 4
    float4 v = *(const float4*)(acc + i);
    float b = b_dt[row];
    float o[4] = {v.x + b, v.y + b, v.z + b, v.w + b};
#pragma unroll
    for (int j = 0; j < 4; ++j)
        o[j] = fmaxf(o[j], 0.f) + log1pf(expf(-fabsf(o[j])));
    *(float4*)(deltaT + i) = make_float4(o[0], o[1], o[2], o[3]);
}

// ---------------------------------------------------------------------------
// Epilogue for GEMM3: acc (1024,1568) -> xd hi/lo splits; cols >= 1536 also
// stored transposed fp32 into BCT[(col-1536)*1024 + row].
// ---------------------------------------------------------------------------
__global__ __launch_bounds__(256) void ep_xdbl_kernel(
    const float* __restrict__ acc,
    ushort_t* __restrict__ xdh, ushort_t* __restrict__ xdl,
    float* __restrict__ BCT)
{
    int i = (blockIdx.x * 256 + threadIdx.x) * 4;
    if (i >= M_ROWS * N_XDBL) return;
    int row = i / N_XDBL;
    int col = i - row * N_XDBL;             // multiple of 4; 1568%4==0
    float4 v = *(const float4*)(acc + i);
    float f[4] = {v.x, v.y, v.z, v.w};
    ushort4_t h, l;
#pragma unroll
    for (int j = 0; j < 4; ++j) { ushort_t hh, ll; split1(f[j], hh, ll); h[j] = hh; l[j] = ll; }
    *(ushort4_t*)(xdh + i) = h;
    *(ushort4_t*)(xdl + i) = l;
    if (col >= D_INNER) {
#pragma unroll
        for (int j = 0; j < 4; ++j)
            BCT[(long)(col + j - D_INNER) * M_ROWS + row] = f[j];
    }
}

// ---------------------------------------------------------------------------
// Depthwise causal conv (width 4) + bias + SiLU.
// ---------------------------------------------------------------------------
__global__ __launch_bounds__(256) void conv_silu_kernel(
    const float* __restrict__ xz,
    const float* __restrict__ conv_w,
    const float* __restrict__ conv_b,
    float* __restrict__ xconvT,
    float* __restrict__ zsiluT,
    ushort_t* __restrict__ xch,
    ushort_t* __restrict__ xcl)
{
    int idx = blockIdx.x * blockDim.x + threadIdx.x;
    if (idx >= M_ROWS * D_INNER) return;
    int d = idx % D_INNER;
    int r = idx / D_INNER;
    int l = r % SEQ;
    float acc = conv_b[d];
#pragma unroll
    for (int k = 0; k < D_CONV; ++k) {
        if (l - (D_CONV - 1) + k >= 0)
            acc = fmaf(conv_w[d * D_CONV + k],
                       xz[(long)(r - (D_CONV - 1 - k)) * N_XZ + d], acc);
    }
    float s = acc / (1.f + expf(-acc));
    xconvT[(long)d * M_ROWS + r] = s;
    ushort_t h, lo;
    split1(s, h, lo);
    xch[idx] = h;
    xcl[idx] = lo;
    float z = xz[(long)r * N_XZ + D_INNER + d];
    zsiluT[(long)d * M_ROWS + r] = z / (1.f + expf(-z));
}

// ---------------------------------------------------------------------------
// Wave-per-(b,d) register scan. No LDS, no barriers. (verified R4/R5)
// ---------------------------------------------------------------------------
__global__ __launch_bounds__(256) void scan_kernel(
    const float* __restrict__ deltaT,
    const float* __restrict__ xconvT,
    const float* __restrict__ zsiluT,
    const float* __restrict__ BCT,     // (32, 1024)
    const float* __restrict__ A_log,
    const float* __restrict__ Dp,
    float* __restrict__ uT)
{
    const int bid = blockIdx.x;
    const int b   = bid / (D_INNER / 4);
    const int dg  = bid % (D_INNER / 4);
    const int tid = threadIdx.x;
    const int w   = tid >> 6;
    const int t   = tid & 63;
    const int d   = dg * 4 + w;
    const int base = b * SEQ;
    const int l0 = 8 * t;

    float dl[8], xr[8], yac[8];
#pragma unroll
    for (int i = 0; i < 8; ++i) {
        dl[i] = deltaT[(long)d * M_ROWS + base + l0 + i];
        xr[i] = xconvT[(long)d * M_ROWS + base + l0 + i];
        yac[i] = 0.f;
    }

    for (int n = 0; n < D_STATE; ++n) {
        const float Adn = -expf(A_log[d * D_STATE + n]);
        const float4* Bp = (const float4*)(BCT + (long)n * M_ROWS + base + l0);
        float4 b0 = Bp[0], b1 = Bp[1];
        float Bv[8] = {b0.x, b0.y, b0.z, b0.w, b1.x, b1.y, b1.z, b1.w};
        float c[8], v[8];
#pragma unroll
        for (int i = 0; i < 8; ++i) {
            c[i] = expf(dl[i] * Adn) + 1e-12f;
            v[i] = fabsf(dl[i] * Bv[i] * xr[i]) + 1e-12f;
        }
        // up-sweep in-lane (levels 0..2)
#pragma unroll
        for (int p = 0; p < 8; p += 2) { v[p+1] = fmaf(c[p+1], v[p+1], v[p]); c[p+1] *= c[p]; }
        v[3] = fmaf(c[3], v[3], v[1]); c[3] *= c[1];
        v[7] = fmaf(c[7], v[7], v[5]); c[7] *= c[5];
        v[7] = fmaf(c[7], v[7], v[3]); c[7] *= c[3];
        // up-sweep cross-lane (levels 3..8)
        float c7 = c[7], v7 = v[7];
#pragma unroll
        for (int h = 1; h <= 32; h <<= 1) {
            float vl = __shfl_up(v7, (unsigned)h);
            float cl = __shfl_up(c7, (unsigned)h);
            bool right = ((t & (2 * h - 1)) == (2 * h - 1));
            if (right) { v7 = fmaf(c7, v7, vl); c7 *= cl; }
        }
        // down-sweep cross-lane (levels 8..3)
#pragma unroll
        for (int h = 32; h >= 1; h >>= 1) {
            float vl = __shfl_up(v7, (unsigned)h);
            float vr = __shfl_down(v7, (unsigned)h);
            bool right = ((t & (2 * h - 1)) == (2 * h - 1));
            bool left  = ((t & (2 * h - 1)) == (h - 1));
            float nv = v7;
            if (right) nv = fmaf(c7, v7, vl);
            if (left)  nv = vr;
            v7 = nv;
        }
        v[7] = v7;
        c[7] = c7;
        // down-sweep in-lane (levels 2..0)
        float tmp;
        tmp = v[7]; v[7] = fmaf(c[7], v[7], v[3]); v[3] = tmp;
        tmp = v[3]; v[3] = fmaf(c[3], v[3], v[1]); v[1] = tmp;
        tmp = v[7]; v[7] = fmaf(c[7], v[7], v[5]); v[5] = tmp;
#pragma unroll
        for (int p = 0; p < 8; p += 2) {
            tmp = v[p+1]; v[p+1] = fmaf(c[p+1], v[p+1], v[p]); v[p] = tmp;
        }
        const float4* Cp = (const float4*)(BCT + (long)(16 + n) * M_ROWS + base + l0);
        float4 c0 = Cp[0], c1 = Cp[1];
        float Cv[8] = {c0.x, c0.y, c0.z, c0.w, c1.x, c1.y, c1.z, c1.w};
#pragma unroll
        for (int i = 0; i < 8; ++i) yac[i] = fmaf(v[i], Cv[i], yac[i]);
    }

    const float Dpd = Dp[d];
#pragma unroll
    for (int i = 0; i < 8; ++i) {
        float uv = fmaf(xr[i], Dpd, yac[i]) * zsiluT[(long)d * M_ROWS + base + l0 + i];
        uT[(long)d * M_ROWS + base + l0 + i] = uv;
    }
}

// ---------------------------------------------------------------------------
// Transpose + split: uT (1536,1024) fp32 -> u hi/lo (1024,1536) bf16.
// ---------------------------------------------------------------------------
__global__ __launch_bounds__(256) void transpose_split_kernel(
    const float* __restrict__ uT, ushort_t* __restrict__ uh, ushort_t* __restrict__ ul)
{
    __shared__ float T[64][65];
    const int m0 = blockIdx.x * 64;
    const int d0 = blockIdx.y * 64;
    const int c  = threadIdx.x & 63;
    const int rr = threadIdx.x >> 6;
#pragma unroll
    for (int p = 0; p < 64; p += 4)
        T[p + rr][c] = uT[(long)(d0 + p + rr) * M_ROWS + m0 + c];
    __syncthreads();
#pragma unroll
    for (int p = 0; p < 64; p += 4) {
        int rm = p + rr;
        float v = T[c][rm];
        ushort_t h, l;
        split1(v, h, l);
        uh[(long)(m0 + rm) * D_INNER + d0 + c] = h;
        ul[(long)(m0 + rm) * D_INNER + d0 + c] = l;
    }
}

// ---------------------------------------------------------------------------
extern "C" void kernel_launch(void* const* d_in, const int* in_sizes, int n_in,
                              void* d_out, int out_size, void* d_ws, size_t ws_size,
                              hipStream_t stream)
{
    (void)in_sizes; (void)n_in; (void)out_size; (void)ws_size;

    const float* x      = (const float*)d_in[0];
    const float* W_in   = (const float*)d_in[1];
    const float* conv_w = (const float*)d_in[2];
    const float* conv_b = (const float*)d_in[3];
    const float* W_x    = (const float*)d_in[4];
    const float* W_dt   = (const float*)d_in[5];
    const float* b_dt   = (const float*)d_in[6];
    const float* A_log  = (const float*)d_in[7];
    const float* Dp     = (const float*)d_in[8];
    const float* W_out  = (const float*)d_in[9];
    float* out = (float*)d_out;

    // workspace: identical 63.6 MB footprint to R5 (x_dbl fp32 replaced by acc)
    float* ws = (float*)d_ws;
    long off = 0;
    float* xz     = ws + off; off += (long)M_ROWS * N_XZ;
    float* deltaT = xz;
    float* uT     = xz + (long)D_INNER * M_ROWS;
    ushort_t* u_h = (ushort_t*)xz;
    ushort_t* u_l = (ushort_t*)xz + (long)M_ROWS * D_INNER;
    float* xconvT = ws + off; off += (long)D_INNER * M_ROWS;
    float* zsiluT = ws + off; off += (long)D_INNER * M_ROWS;
    float* accbuf = ws + off; off += (long)M_ROWS * N_XDBL;    // shared acc3/acc4
    ushort_t* w1_h = (ushort_t*)(ws + off);
    ushort_t* w1_l = w1_h + (long)N_XZ * D_MODEL;   off += (long)N_XZ * D_MODEL;
    ushort_t* w2_h = (ushort_t*)(ws + off);
    ushort_t* w2_l = w2_h + (long)N_XDBL * D_INNER; off += (long)N_XDBL * D_INNER;
    ushort_t* x_h = (ushort_t*)(ws + off);
    ushort_t* x_l = x_h + (long)M_ROWS * D_MODEL;   off += (long)M_ROWS * D_MODEL;
    ushort_t* xc_h = (ushort_t*)(ws + off);
    ushort_t* xc_l = xc_h + (long)M_ROWS * D_INNER; off += (long)M_ROWS * D_INNER;
    ushort_t* xd_h = (ushort_t*)(ws + off);
    ushort_t* xd_l = xd_h + (long)M_ROWS * N_XDBL;  off += (long)M_ROWS * N_XDBL;
    float* BCT = ws + off; off += (long)2 * D_STATE * M_ROWS;

    dim3 blk(256);
    dim3 wblk(64);

    hipLaunchKernelGGL(split_kernel, dim3((M_ROWS * D_MODEL) / 1024), blk, 0, stream,
                       x, x_h, x_l, M_ROWS * D_MODEL);
    hipLaunchKernelGGL(split_kernel, dim3((N_XZ * D_MODEL) / 1024), blk, 0, stream,
                       W_in, w1_h, w1_l, N_XZ * D_MODEL);
    // 1) xz = x @ W_in^T  (M=1024,N=3072,K=768) — direct store, 768 waves
    hipLaunchKernelGGL((gemm_mfma<0>), dim3(N_XZ / 64, M_ROWS / 64, 1), wblk, 0, stream,
                       x_h, x_l, D_MODEL, w1_h, w1_l, D_MODEL,
                       xz, N_XZ, N_XZ, D_MODEL);
    hipLaunchKernelGGL(split_kernel, dim3((D_INNER * D_INNER) / 1024), blk, 0, stream,
                       W_dt, w1_h, w1_l, D_INNER * D_INNER);
    // 2) conv + silu
    hipLaunchKernelGGL(conv_silu_kernel, dim3((M_ROWS * D_INNER) / 256), blk, 0, stream,
                       xz, conv_w, conv_b, xconvT, zsiluT, xc_h, xc_l);
    hipLaunchKernelGGL(split_kernel, dim3((N_XDBL * D_INNER) / 1024), blk, 0, stream,
                       W_x, w2_h, w2_l, N_XDBL * D_INNER);
    // 3) x_dbl: acc = xconv @ W_x^T  (M=1024,N=1568,K=1536), split-K=2, 800 waves
    hipMemsetAsync(accbuf, 0, (size_t)M_ROWS * N_XDBL * 4, stream);
    hipLaunchKernelGGL((gemm_mfma<1>), dim3((N_XDBL + 63) / 64, M_ROWS / 64, 2), wblk, 0, stream,
                       xc_h, xc_l, D_INNER, w2_h, w2_l, D_INNER,
                       accbuf, N_XDBL, N_XDBL, D_INNER / 2);
    hipLaunchKernelGGL(ep_xdbl_kernel, dim3((M_ROWS * N_XDBL) / 1024), blk, 0, stream,
                       accbuf, xd_h, xd_l, BCT);
    hipLaunchKernelGGL(split_kernel, dim3((D_MODEL * D_INNER) / 1024), blk, 0, stream,
                       W_out, w2_h, w2_l, D_MODEL * D_INNER);
    // 4) acc = W_dt @ x_dbl^T  (M=1536,N=1024,K=1536), split-K=2, 768 waves
    hipMemsetAsync(accbuf, 0, (size_t)D_INNER * M_ROWS * 4, stream);
    hipLaunchKernelGGL((gemm_mfma<1>), dim3(M_ROWS / 64, D_INNER / 64, 2), wblk, 0, stream,
                       w1_h, w1_l, D_INNER, xd_h, xd_l, N_XDBL,
                       accbuf, M_ROWS, M_ROWS, D_INNER / 2);
    hipLaunchKernelGGL(ep_softplus_kernel, dim3((D_INNER * M_ROWS) / 1024), blk, 0, stream,
                       accbuf, b_dt, deltaT);
    // 5) scan -> uT
    hipLaunchKernelGGL(scan_kernel, dim3(BATCH * (D_INNER / 4)), blk, 0, stream,
                       deltaT, xconvT, zsiluT, BCT, A_log, Dp, uT);
    // 5b) transpose+split uT -> u hi/lo
    hipLaunchKernelGGL(transpose_split_kernel, dim3(M_ROWS / 64, D_INNER / 64), blk, 0, stream,
                       uT, u_h, u_l);
    // 6) out = u @ W_out^T  (M=1024,N=768,K=1536), split-K=2, 384 waves
    hipMemsetAsync(out, 0, (size_t)M_ROWS * D_MODEL * 4, stream);
    hipLaunchKernelGGL((gemm_mfma<1>), dim3(D_MODEL / 64, M_ROWS / 64, 2), wblk, 0, stream,
                       u_h, u_l, D_INNER, w2_h, w2_l, D_INNER,
                       out, D_MODEL, D_MODEL, D_INNER / 2);
}

// Round 7
// 318.984 us; speedup vs baseline: 1.3634x; 1.3634x over previous
//
#include <hip/hip_runtime.h>
#include <math.h>

#define D_MODEL 768
#define D_STATE 16
#define D_CONV  4
#define D_INNER 1536
#define BATCH   2
#define SEQ     512
#define M_ROWS  (BATCH * SEQ)            // 1024
#define N_XZ    (2 * D_INNER)            // 3072
#define N_XDBL  (D_INNER + 2 * D_STATE)  // 1568

typedef short  short8 __attribute__((ext_vector_type(8)));
typedef float  f32x4  __attribute__((ext_vector_type(4)));
typedef unsigned short ushort_t;
typedef ushort_t ushort4_t __attribute__((ext_vector_type(4)));

// ---- manual bf16 helpers (RNE), raw ushort storage ----
__device__ __forceinline__ ushort_t f2bf(float f) {
    unsigned int u = __float_as_uint(f);
    return (ushort_t)((u + 0x7fffu + ((u >> 16) & 1u)) >> 16);
}
__device__ __forceinline__ float bf2f(ushort_t s) {
    return __uint_as_float((unsigned int)s << 16);
}
__device__ __forceinline__ void split1(float x, ushort_t& h, ushort_t& l) {
    h = f2bf(x);
    l = f2bf(x - bf2f(h));
}

// ---------------------------------------------------------------------------
// Split fp32 -> (hi, lo) bf16.  n multiple of 1024; 4 elements/thread.
// ---------------------------------------------------------------------------
__global__ __launch_bounds__(256) void split_kernel(
    const float* __restrict__ in, ushort_t* __restrict__ hi,
    ushort_t* __restrict__ lo, int n)
{
    int i = (blockIdx.x * 256 + threadIdx.x) * 4;
    if (i >= n) return;
    float4 v = *(const float4*)(in + i);
    ushort_t h0,h1,h2,h3,l0,l1,l2,l3;
    split1(v.x,h0,l0); split1(v.y,h1,l1); split1(v.z,h2,l2); split1(v.w,h3,l3);
    hi[i+0]=h0; hi[i+1]=h1; hi[i+2]=h2; hi[i+3]=h3;
    lo[i+0]=l0; lo[i+1]=l1; lo[i+2]=l2; lo[i+3]=l3;
}

// ---------------------------------------------------------------------------
// Split-bf16 MFMA GEMM — one wave per block, 64x64 tile, no LDS, no barriers.
// DOUBLE-buffered fragment sets; __launch_bounds__(64,1) unlocks ~512 VGPRs
// so both sets (256 regs) + 64 acc regs fit spill-free (m08: safe to ~450).
// grid.z = K-chunk (kc columns each, kc % 64 == 0); chunk z stores to Cz.
// A (M,K), B (N,K) hi/lo bf16.  3-product split: Al*Bh + Ah*Bl + Ah*Bh.
// N tail: B row clamped for loads, store guarded.
// ---------------------------------------------------------------------------
__global__ __launch_bounds__(64, 1) void gemm_mfma(
    const ushort_t* __restrict__ Ah, const ushort_t* __restrict__ Al, int lda,
    const ushort_t* __restrict__ Bh, const ushort_t* __restrict__ Bl, int ldb,
    float* __restrict__ C0, float* __restrict__ C1, int ldc,
    int N, int kc)
{
    const int lane = threadIdx.x;
    const int bm = blockIdx.y * 64;
    const int bn = blockIdx.x * 64;
    const int lr = lane & 15;
    const int lq = lane >> 4;
    const long k0 = (long)blockIdx.z * kc + lq * 8;
    float* __restrict__ C = blockIdx.z ? C1 : C0;

    long oA[4], oB[4];
#pragma unroll
    for (int i = 0; i < 4; ++i) {
        oA[i] = (long)(bm + i * 16 + lr) * lda + k0;
        int rB = bn + i * 16 + lr;
        if (rB >= N) rB = N - 1;               // clamp: in-buffer, discarded
        oB[i] = (long)rB * ldb + k0;
    }

    f32x4 acc[4][4] = {};
    short8 a0h[4], a0l[4], b0h[4], b0l[4];
    short8 a1h[4], a1l[4], b1h[4], b1l[4];

    auto loadset = [&](short8* ah, short8* al, short8* bh, short8* bl, int kk) {
#pragma unroll
        for (int i = 0; i < 4; ++i) {
            ah[i] = *(const short8*)(Ah + oA[i] + kk);
            al[i] = *(const short8*)(Al + oA[i] + kk);
            bh[i] = *(const short8*)(Bh + oB[i] + kk);
            bl[i] = *(const short8*)(Bl + oB[i] + kk);
        }
    };
    auto mfmaset = [&](short8* ah, short8* al, short8* bh, short8* bl) {
#pragma unroll
        for (int mt = 0; mt < 4; ++mt)
#pragma unroll
            for (int nt = 0; nt < 4; ++nt) {
                acc[mt][nt] = __builtin_amdgcn_mfma_f32_16x16x32_bf16(al[mt], bh[nt], acc[mt][nt], 0, 0, 0);
                acc[mt][nt] = __builtin_amdgcn_mfma_f32_16x16x32_bf16(ah[mt], bl[nt], acc[mt][nt], 0, 0, 0);
                acc[mt][nt] = __builtin_amdgcn_mfma_f32_16x16x32_bf16(ah[mt], bh[nt], acc[mt][nt], 0, 0, 0);
            }
    };

    const int nPair = kc >> 6;
    loadset(a0h, a0l, b0h, b0l, 0);
    int k = 0;
    for (int it = 0; it < nPair; ++it) {
        loadset(a1h, a1l, b1h, b1l, k + 32);     // in flight during MFMA set 0
        mfmaset(a0h, a0l, b0h, b0l);
        if (it + 1 < nPair)
            loadset(a0h, a0l, b0h, b0l, k + 64); // in flight during MFMA set 1
        mfmaset(a1h, a1l, b1h, b1l);
        k += 64;
    }

    // C/D layout: col = lane&15, row = (lane>>4)*4 + reg  [m89/m91]
    const int col0 = lane & 15;
    const int quad = lane >> 4;
#pragma unroll
    for (int mt = 0; mt < 4; ++mt)
#pragma unroll
        for (int nt = 0; nt < 4; ++nt)
#pragma unroll
            for (int r = 0; r < 4; ++r) {
                int row = bm + mt * 16 + quad * 4 + r;
                int col = bn + nt * 16 + col0;
                if (col >= N) continue;
                C[(long)row * ldc + col] = acc[mt][nt][r];
            }
}

// ---------------------------------------------------------------------------
// GEMM3 epilogue: acc = p0 + p1 (1024,1568) -> xd hi/lo split; cols >= 1536
// also stored transposed fp32 into BCT[(col-1536)*1024 + row].
// ---------------------------------------------------------------------------
__global__ __launch_bounds__(256) void ep_xdbl_kernel(
    const float* __restrict__ p0, const float* __restrict__ p1,
    ushort_t* __restrict__ xdh, ushort_t* __restrict__ xdl,
    float* __restrict__ BCT)
{
    int i = (blockIdx.x * 256 + threadIdx.x) * 4;
    if (i >= M_ROWS * N_XDBL) return;
    int row = i / N_XDBL;
    int col = i - row * N_XDBL;             // multiple of 4; 1568%4==0
    float4 v0 = *(const float4*)(p0 + i);
    float4 v1 = *(const float4*)(p1 + i);
    float f[4] = {v0.x + v1.x, v0.y + v1.y, v0.z + v1.z, v0.w + v1.w};
    ushort4_t h, l;
#pragma unroll
    for (int j = 0; j < 4; ++j) { ushort_t hh, ll; split1(f[j], hh, ll); h[j] = hh; l[j] = ll; }
    *(ushort4_t*)(xdh + i) = h;
    *(ushort4_t*)(xdl + i) = l;
    if (col >= D_INNER) {
#pragma unroll
        for (int j = 0; j < 4; ++j)
            BCT[(long)(col + j - D_INNER) * M_ROWS + row] = f[j];
    }
}

// ---------------------------------------------------------------------------
// GEMM4 epilogue: deltaT = softplus(p0 + p1 + b_dt[row]); (1536,1024) fp32.
// ---------------------------------------------------------------------------
__global__ __launch_bounds__(256) void ep_softplus_kernel(
    const float* __restrict__ p0, const float* __restrict__ p1,
    const float* __restrict__ b_dt, float* __restrict__ deltaT)
{
    int i = (blockIdx.x * 256 + threadIdx.x) * 4;
    if (i >= D_INNER * M_ROWS) return;
    int row = i >> 10;                      // /1024
    float4 v0 = *(const float4*)(p0 + i);
    float4 v1 = *(const float4*)(p1 + i);
    float b = b_dt[row];
    float o[4] = {v0.x + v1.x + b, v0.y + v1.y + b, v0.z + v1.z + b, v0.w + v1.w + b};
#pragma unroll
    for (int j = 0; j < 4; ++j)
        o[j] = fmaxf(o[j], 0.f) + log1pf(expf(-fabsf(o[j])));
    *(float4*)(deltaT + i) = make_float4(o[0], o[1], o[2], o[3]);
}

// ---------------------------------------------------------------------------
// GEMM6 epilogue: out = p0 + p1  (1024*768 fp32)
// ---------------------------------------------------------------------------
__global__ __launch_bounds__(256) void ep_merge_kernel(
    const float* __restrict__ p0, const float* __restrict__ p1,
    float* __restrict__ out)
{
    int i = (blockIdx.x * 256 + threadIdx.x) * 4;
    if (i >= M_ROWS * D_MODEL) return;
    float4 v0 = *(const float4*)(p0 + i);
    float4 v1 = *(const float4*)(p1 + i);
    *(float4*)(out + i) = make_float4(v0.x + v1.x, v0.y + v1.y, v0.z + v1.z, v0.w + v1.w);
}

// ---------------------------------------------------------------------------
// Depthwise causal conv (width 4) + bias + SiLU.
// ---------------------------------------------------------------------------
__global__ __launch_bounds__(256) void conv_silu_kernel(
    const float* __restrict__ xz,
    const float* __restrict__ conv_w,
    const float* __restrict__ conv_b,
    float* __restrict__ xconvT,
    float* __restrict__ zsiluT,
    ushort_t* __restrict__ xch,
    ushort_t* __restrict__ xcl)
{
    int idx = blockIdx.x * blockDim.x + threadIdx.x;
    if (idx >= M_ROWS * D_INNER) return;
    int d = idx % D_INNER;
    int r = idx / D_INNER;
    int l = r % SEQ;
    float acc = conv_b[d];
#pragma unroll
    for (int k = 0; k < D_CONV; ++k) {
        if (l - (D_CONV - 1) + k >= 0)
            acc = fmaf(conv_w[d * D_CONV + k],
                       xz[(long)(r - (D_CONV - 1 - k)) * N_XZ + d], acc);
    }
    float s = acc / (1.f + expf(-acc));
    xconvT[(long)d * M_ROWS + r] = s;
    ushort_t h, lo;
    split1(s, h, lo);
    xch[idx] = h;
    xcl[idx] = lo;
    float z = xz[(long)r * N_XZ + D_INNER + d];
    zsiluT[(long)d * M_ROWS + r] = z / (1.f + expf(-z));
}

// ---------------------------------------------------------------------------
// Wave-per-(b,d) register scan. No LDS, no barriers. (verified R4/R5)
// ---------------------------------------------------------------------------
__global__ __launch_bounds__(256) void scan_kernel(
    const float* __restrict__ deltaT,
    const float* __restrict__ xconvT,
    const float* __restrict__ zsiluT,
    const float* __restrict__ BCT,     // (32, 1024)
    const float* __restrict__ A_log,
    const float* __restrict__ Dp,
    float* __restrict__ uT)
{
    const int bid = blockIdx.x;
    const int b   = bid / (D_INNER / 4);
    const int dg  = bid % (D_INNER / 4);
    const int tid = threadIdx.x;
    const int w   = tid >> 6;
    const int t   = tid & 63;
    const int d   = dg * 4 + w;
    const int base = b * SEQ;
    const int l0 = 8 * t;

    float dl[8], xr[8], yac[8];
#pragma unroll
    for (int i = 0; i < 8; ++i) {
        dl[i] = deltaT[(long)d * M_ROWS + base + l0 + i];
        xr[i] = xconvT[(long)d * M_ROWS + base + l0 + i];
        yac[i] = 0.f;
    }

    for (int n = 0; n < D_STATE; ++n) {
        const float Adn = -expf(A_log[d * D_STATE + n]);
        const float4* Bp = (const float4*)(BCT + (long)n * M_ROWS + base + l0);
        float4 b0 = Bp[0], b1 = Bp[1];
        float Bv[8] = {b0.x, b0.y, b0.z, b0.w, b1.x, b1.y, b1.z, b1.w};
        float c[8], v[8];
#pragma unroll
        for (int i = 0; i < 8; ++i) {
            c[i] = expf(dl[i] * Adn) + 1e-12f;
            v[i] = fabsf(dl[i] * Bv[i] * xr[i]) + 1e-12f;
        }
#pragma unroll
        for (int p = 0; p < 8; p += 2) { v[p+1] = fmaf(c[p+1], v[p+1], v[p]); c[p+1] *= c[p]; }
        v[3] = fmaf(c[3], v[3], v[1]); c[3] *= c[1];
        v[7] = fmaf(c[7], v[7], v[5]); c[7] *= c[5];
        v[7] = fmaf(c[7], v[7], v[3]); c[7] *= c[3];
        float c7 = c[7], v7 = v[7];
#pragma unroll
        for (int h = 1; h <= 32; h <<= 1) {
            float vl = __shfl_up(v7, (unsigned)h);
            float cl = __shfl_up(c7, (unsigned)h);
            bool right = ((t & (2 * h - 1)) == (2 * h - 1));
            if (right) { v7 = fmaf(c7, v7, vl); c7 *= cl; }
        }
#pragma unroll
        for (int h = 32; h >= 1; h >>= 1) {
            float vl = __shfl_up(v7, (unsigned)h);
            float vr = __shfl_down(v7, (unsigned)h);
            bool right = ((t & (2 * h - 1)) == (2 * h - 1));
            bool left  = ((t & (2 * h - 1)) == (h - 1));
            float nv = v7;
            if (right) nv = fmaf(c7, v7, vl);
            if (left)  nv = vr;
            v7 = nv;
        }
        v[7] = v7;
        c[7] = c7;
        float tmp;
        tmp = v[7]; v[7] = fmaf(c[7], v[7], v[3]); v[3] = tmp;
        tmp = v[3]; v[3] = fmaf(c[3], v[3], v[1]); v[1] = tmp;
        tmp = v[7]; v[7] = fmaf(c[7], v[7], v[5]); v[5] = tmp;
#pragma unroll
        for (int p = 0; p < 8; p += 2) {
            tmp = v[p+1]; v[p+1] = fmaf(c[p+1], v[p+1], v[p]); v[p] = tmp;
        }
        const float4* Cp = (const float4*)(BCT + (long)(16 + n) * M_ROWS + base + l0);
        float4 c0 = Cp[0], c1 = Cp[1];
        float Cv[8] = {c0.x, c0.y, c0.z, c0.w, c1.x, c1.y, c1.z, c1.w};
#pragma unroll
        for (int i = 0; i < 8; ++i) yac[i] = fmaf(v[i], Cv[i], yac[i]);
    }

    const float Dpd = Dp[d];
#pragma unroll
    for (int i = 0; i < 8; ++i) {
        float uv = fmaf(xr[i], Dpd, yac[i]) * zsiluT[(long)d * M_ROWS + base + l0 + i];
        uT[(long)d * M_ROWS + base + l0 + i] = uv;
    }
}

// ---------------------------------------------------------------------------
// Transpose + split: uT (1536,1024) fp32 -> u hi/lo (1024,1536) bf16.
// ---------------------------------------------------------------------------
__global__ __launch_bounds__(256) void transpose_split_kernel(
    const float* __restrict__ uT, ushort_t* __restrict__ uh, ushort_t* __restrict__ ul)
{
    __shared__ float T[64][65];
    const int m0 = blockIdx.x * 64;
    const int d0 = blockIdx.y * 64;
    const int c  = threadIdx.x & 63;
    const int rr = threadIdx.x >> 6;
#pragma unroll
    for (int p = 0; p < 64; p += 4)
        T[p + rr][c] = uT[(long)(d0 + p + rr) * M_ROWS + m0 + c];
    __syncthreads();
#pragma unroll
    for (int p = 0; p < 64; p += 4) {
        int rm = p + rr;
        float v = T[c][rm];
        ushort_t h, l;
        split1(v, h, l);
        uh[(long)(m0 + rm) * D_INNER + d0 + c] = h;
        ul[(long)(m0 + rm) * D_INNER + d0 + c] = l;
    }
}

// ---------------------------------------------------------------------------
extern "C" void kernel_launch(void* const* d_in, const int* in_sizes, int n_in,
                              void* d_out, int out_size, void* d_ws, size_t ws_size,
                              hipStream_t stream)
{
    (void)in_sizes; (void)n_in; (void)out_size; (void)ws_size;

    const float* x      = (const float*)d_in[0];
    const float* W_in   = (const float*)d_in[1];
    const float* conv_w = (const float*)d_in[2];
    const float* conv_b = (const float*)d_in[3];
    const float* W_x    = (const float*)d_in[4];
    const float* W_dt   = (const float*)d_in[5];
    const float* b_dt   = (const float*)d_in[6];
    const float* A_log  = (const float*)d_in[7];
    const float* Dp     = (const float*)d_in[8];
    const float* W_out  = (const float*)d_in[9];
    float* out = (float*)d_out;

    // workspace: same 63.6 MB footprint as R5. Split-K partials live in dead
    // regions: xz (12.6 MB, dead after conv) = {lo: deltaT / GEMM4-p1-alt,
    // hi: uT}; acc0 region = old x_dbl slot.
    float* ws = (float*)d_ws;
    long off = 0;
    float* xz     = ws + off; off += (long)M_ROWS * N_XZ;
    float* xz_lo  = xz;                                  // 6.29 MB
    float* xz_hi  = xz + (long)D_INNER * M_ROWS;         // 6.29 MB
    float* deltaT = xz_lo;
    float* uT     = xz_hi;
    ushort_t* u_h = (ushort_t*)xz_lo;
    ushort_t* u_l = (ushort_t*)xz_lo + (long)M_ROWS * D_INNER;
    float* xconvT = ws + off; off += (long)D_INNER * M_ROWS;
    float* zsiluT = ws + off; off += (long)D_INNER * M_ROWS;
    float* acc0   = ws + off; off += (long)M_ROWS * N_XDBL;   // 6.42 MB
    ushort_t* w1_h = (ushort_t*)(ws + off);
    ushort_t* w1_l = w1_h + (long)N_XZ * D_MODEL;   off += (long)N_XZ * D_MODEL;
    ushort_t* w2_h = (ushort_t*)(ws + off);
    ushort_t* w2_l = w2_h + (long)N_XDBL * D_INNER; off += (long)N_XDBL * D_INNER;
    ushort_t* x_h = (ushort_t*)(ws + off);
    ushort_t* x_l = x_h + (long)M_ROWS * D_MODEL;   off += (long)M_ROWS * D_MODEL;
    ushort_t* xc_h = (ushort_t*)(ws + off);
    ushort_t* xc_l = xc_h + (long)M_ROWS * D_INNER; off += (long)M_ROWS * D_INNER;
    ushort_t* xd_h = (ushort_t*)(ws + off);
    ushort_t* xd_l = xd_h + (long)M_ROWS * N_XDBL;  off += (long)M_ROWS * N_XDBL;
    float* BCT = ws + off; off += (long)2 * D_STATE * M_ROWS;

    dim3 blk(256);
    dim3 wblk(64);

    hipLaunchKernelGGL(split_kernel, dim3((M_ROWS * D_MODEL) / 1024), blk, 0, stream,
                       x, x_h, x_l, M_ROWS * D_MODEL);
    hipLaunchKernelGGL(split_kernel, dim3((N_XZ * D_MODEL) / 1024), blk, 0, stream,
                       W_in, w1_h, w1_l, N_XZ * D_MODEL);
    // 1) xz = x @ W_in^T  (M=1024,N=3072,K=768) — single chunk, 768 waves
    hipLaunchKernelGGL(gemm_mfma, dim3(N_XZ / 64, M_ROWS / 64, 1), wblk, 0, stream,
                       x_h, x_l, D_MODEL, w1_h, w1_l, D_MODEL,
                       xz, xz, N_XZ, N_XZ, D_MODEL);
    hipLaunchKernelGGL(split_kernel, dim3((D_INNER * D_INNER) / 1024), blk, 0, stream,
                       W_dt, w1_h, w1_l, D_INNER * D_INNER);
    // 2) conv + silu  (consumes xz fp32; xz region free afterwards)
    hipLaunchKernelGGL(conv_silu_kernel, dim3((M_ROWS * D_INNER) / 256), blk, 0, stream,
                       xz, conv_w, conv_b, xconvT, zsiluT, xc_h, xc_l);
    hipLaunchKernelGGL(split_kernel, dim3((N_XDBL * D_INNER) / 1024), blk, 0, stream,
                       W_x, w2_h, w2_l, N_XDBL * D_INNER);
    // 3) xconv @ W_x^T  (M=1024,N=1568,K=1536) split-K=2 -> acc0 / xz (p1 spans lo+hi)
    hipLaunchKernelGGL(gemm_mfma, dim3((N_XDBL + 63) / 64, M_ROWS / 64, 2), wblk, 0, stream,
                       xc_h, xc_l, D_INNER, w2_h, w2_l, D_INNER,
                       acc0, xz, N_XDBL, N_XDBL, D_INNER / 2);
    hipLaunchKernelGGL(ep_xdbl_kernel, dim3((M_ROWS * N_XDBL) / 1024), blk, 0, stream,
                       acc0, xz, xd_h, xd_l, BCT);
    hipLaunchKernelGGL(split_kernel, dim3((D_MODEL * D_INNER) / 1024), blk, 0, stream,
                       W_out, w2_h, w2_l, D_MODEL * D_INNER);
    // 4) W_dt @ x_dbl^T  (M=1536,N=1024,K=1536) split-K=2 -> acc0 / xz_hi
    hipLaunchKernelGGL(gemm_mfma, dim3(M_ROWS / 64, D_INNER / 64, 2), wblk, 0, stream,
                       w1_h, w1_l, D_INNER, xd_h, xd_l, N_XDBL,
                       acc0, xz_hi, M_ROWS, M_ROWS, D_INNER / 2);
    hipLaunchKernelGGL(ep_softplus_kernel, dim3((D_INNER * M_ROWS) / 1024), blk, 0, stream,
                       acc0, xz_hi, b_dt, deltaT);
    // 5) scan -> uT (xz_hi; GEMM4 partial already consumed)
    hipLaunchKernelGGL(scan_kernel, dim3(BATCH * (D_INNER / 4)), blk, 0, stream,
                       deltaT, xconvT, zsiluT, BCT, A_log, Dp, uT);
    // 5b) transpose+split uT -> u hi/lo (overwrites deltaT region, now dead)
    hipLaunchKernelGGL(transpose_split_kernel, dim3(M_ROWS / 64, D_INNER / 64), blk, 0, stream,
                       uT, u_h, u_l);
    // 6) u @ W_out^T  (M=1024,N=768,K=1536) split-K=2 -> acc0[0] / acc0[+3.1MB]
    {
        float* p0 = acc0;
        float* p1 = acc0 + (long)M_ROWS * D_MODEL;
        hipLaunchKernelGGL(gemm_mfma, dim3(D_MODEL / 64, M_ROWS / 64, 2), wblk, 0, stream,
                           u_h, u_l, D_INNER, w2_h, w2_l, D_INNER,
                           p0, p1, D_MODEL, D_MODEL, D_INNER / 2);
        hipLaunchKernelGGL(ep_merge_kernel, dim3((M_ROWS * D_MODEL) / 1024), blk, 0, stream,
                           p0, p1, out);
    }
}